// Round 13
// baseline (308.802 us; speedup 1.0000x reference)
//
#include <hip/hip_runtime.h>
#include <cstdint>

// Int8 OPT attention block: B=2,T=2048,D=2048,H=32,HD=64
#define A_PROJ 3e-4f
#define A_QK   2e-5f
#define A_PV   1e-2f
#define A_OUT  1e-4f

#define NB 2
#define NT 2048
#define ND 2048
#define NH 32
#define NHD 64
#define NM (NB*NT)   // 4096 = B*T rows

typedef int v4i __attribute__((ext_vector_type(4)));

__device__ __forceinline__ int8_t sat8(float y) {
  float r = rintf(y);                      // half-to-even == np.round
  r = fminf(fmaxf(r, -128.f), 127.f);
  return (int8_t)(int)r;
}

// raw v_exp_f32: D = 2^x (device builtin; __exp2f collides with glibc macros)
__device__ __forceinline__ float exp2_fast(float x) {
  return __builtin_amdgcn_exp2f(x);
}

// async global->LDS, 16B/lane; LDS dest = wave-uniform base + lane*16
__device__ __forceinline__ void gl2lds16(const int8_t* g, int8_t* l) {
  __builtin_amdgcn_global_load_lds(
      (const __attribute__((address_space(1))) void*)g,
      (__attribute__((address_space(3))) void*)l, 16, 0, 0);
}

// pack 4 float low-bytes into one u32: bytes [b0,b1,b2,b3] = low bytes of f0..f3
__device__ __forceinline__ uint32_t pack_lo4(float f0, float f1, float f2, float f3) {
  uint32_t u0 = __float_as_uint(f0), u1 = __float_as_uint(f1);
  uint32_t u2 = __float_as_uint(f2), u3 = __float_as_uint(f3);
  uint32_t lo = __builtin_amdgcn_perm(u1, u0, 0x04000400u);  // [f0.b0, f1.b0, x, x]
  uint32_t hi = __builtin_amdgcn_perm(u3, u2, 0x04000400u);  // [f2.b0, f3.b0, x, x]
  return __builtin_amdgcn_perm(hi, lo, 0x05040100u);         // [f0,f1,f2,f3] low bytes
}

// XCD-region swizzle for a 32x16 tile grid (R15: FETCH -20% verified).
__device__ __forceinline__ void xcd_map(int lid, int& bx, int& by) {
  int xcd = lid & 7, j = lid >> 3;        // j in [0,64)
  bx = (xcd & 3) * 8 + (j & 7);           // [0,32)
  by = (xcd >> 2) * 8 + (j >> 3);         // [0,16)
}

// ---------------- fused pack: int32 -> int8 for X + 4 weights ----------------
#define NWW (ND*ND/4)      // 1048576 words = 2^20
__global__ void pack_all(const int* __restrict__ X,
                         const int* __restrict__ W0, const int* __restrict__ W1,
                         const int* __restrict__ W2, const int* __restrict__ W3,
                         int8_t* __restrict__ dX, int8_t* __restrict__ dW0,
                         int8_t* __restrict__ dW1, int8_t* __restrict__ dW2,
                         int8_t* __restrict__ dW3) {
  int i = blockIdx.x * blockDim.x + threadIdx.x;
  const int nx = NM*ND/4;
  const int* src; int8_t* dst; int off;
  if (i < nx) { src = X; dst = dX; off = i; }
  else {
    int j = i - nx;
    int r = j >> 20;            // NWW = 2^20
    off = j & (NWW - 1);
    src = (r == 0) ? W0 : (r == 1) ? W1 : (r == 2) ? W2 : W3;
    dst = (r == 0) ? dW0 : (r == 1) ? dW1 : (r == 2) ? dW2 : dW3;
  }
  int4 v = ((const int4*)src)[off];
  uint32_t p = (uint32_t)(v.x & 255) | ((uint32_t)(v.y & 255) << 8) |
               ((uint32_t)(v.z & 255) << 16) | ((uint32_t)(v.w & 255) << 24);
  ((uint32_t*)dst)[off] = p;
}

// ---------------- QKV projection: all 3 outputs per block (R16, verified win) ----------------
// One block computes Q,K,V for its (bx,by) tile. X panel staged ONCE; per K-step
// each wave runs 48 MFMAs (~960cy) > ~900cy staging latency -> prefetch-dbuf +
// single __syncthreads is self-covering. LDS S[2][4][128][64] = 64KB, 2 blocks/CU.
__global__ __launch_bounds__(256, 2) void gemm_qkv(
    const int8_t* __restrict__ X,
    const int8_t* __restrict__ Wq, const int8_t* __restrict__ Wk, const int8_t* __restrict__ Wv,
    const int* __restrict__ bq, const int* __restrict__ bk, const int* __restrict__ bv,
    int8_t* __restrict__ Qh, int8_t* __restrict__ Kh, int8_t* __restrict__ Vt)
{
  __shared__ __align__(16) int8_t S[2][4][128][64];   // [buf][plane][row][chunk]
  int bx, by;
  xcd_map(blockIdx.x + 32 * blockIdx.y, bx, by);
  const int m0 = bx * 128, n0 = by * 128;
  const int tid = threadIdx.x, lane = tid & 63, wave = tid >> 6;
  const int wm = wave >> 1, wn = wave & 1;
  const int l15 = lane & 15, quad = lane >> 4;

  const int srow = lane >> 2;                               // staging row within 16-block
  const int scol = (((lane & 3) ^ ((lane >> 3) & 3)) * 16); // swizzled logical chunk
  const int rqcol = (quad ^ ((l15 >> 1) & 3)) * 16;         // frag-read stored chunk

  // staging: 32 slots of 16 rows (8 X + 8 Wq + 8 Wk + 8 Wv), 4 waves x 8 issues
  const int8_t* srcp[8];
  int8_t* dstp[8];
  #pragma unroll
  for (int j = 0; j < 8; ++j) {
    int slot = j * 4 + wave;          // 0..31
    int rblk = slot & 7;
    int sel  = slot >> 3;             // 0=X, 1=Wq, 2=Wk, 3=Wv
    int row  = rblk * 16 + srow;
    const int8_t* base = (sel == 0) ? &X[(size_t)(m0 + row) * ND]
                                    : (sel == 1) ? &Wq[(size_t)(n0 + row) * ND]
                                    : (sel == 2) ? &Wk[(size_t)(n0 + row) * ND]
                                                 : &Wv[(size_t)(n0 + row) * ND];
    srcp[j] = base + scol;
    dstp[j] = &S[0][sel][rblk * 16][0];
  }

  v4i acc[3][4][4];
  const v4i vzero = {0, 0, 0, 0};
  #pragma unroll
  for (int z = 0; z < 3; ++z)
    #pragma unroll
    for (int i = 0; i < 4; ++i)
      #pragma unroll
      for (int j = 0; j < 4; ++j) acc[z][i][j] = vzero;

  // prologue: stage step 0 into buf 0
  #pragma unroll
  for (int j = 0; j < 8; ++j) gl2lds16(srcp[j], dstp[j]);
  __syncthreads();

  int cur = 0;
  for (int k0 = 64; k0 <= ND; k0 += 64) {       // 32 compute steps
    if (k0 < ND) {
      const int boff = (cur ^ 1) * 32768;       // buffer stride = 4*128*64
      #pragma unroll
      for (int j = 0; j < 8; ++j) gl2lds16(srcp[j] + k0, dstp[j] + boff);
    }
    v4i a[4];
    #pragma unroll
    for (int mt = 0; mt < 4; ++mt)
      a[mt] = *(const v4i*)&S[cur][0][wm*64 + mt*16 + l15][rqcol];
    #pragma unroll
    for (int z = 0; z < 3; ++z)
      #pragma unroll
      for (int nt = 0; nt < 4; ++nt) {
        v4i b = *(const v4i*)&S[cur][1 + z][wn*64 + nt*16 + l15][rqcol];
        #pragma unroll
        for (int mt = 0; mt < 4; ++mt)
          acc[z][mt][nt] = __builtin_amdgcn_mfma_i32_16x16x64_i8(a[mt], b, acc[z][mt][nt], 0, 0, 0);
      }
    __syncthreads();
    cur ^= 1;
  }

  // epilogue: z=0 -> Qh, z=1 -> Kh, z=2 -> Vt (u32-packed)
  #pragma unroll
  for (int z = 0; z < 3; ++z) {
    const int* bias = (z == 0) ? bq : (z == 1) ? bk : bv;
    float bf[4];
    #pragma unroll
    for (int nt = 0; nt < 4; ++nt) bf[nt] = (float)bias[n0 + wn*64 + nt*16 + l15];
    if (z == 2) {
      #pragma unroll
      for (int mt = 0; mt < 4; ++mt)
        #pragma unroll
        for (int nt = 0; nt < 4; ++nt) {
          int tbase = (m0 + wm*64 + mt*16 + quad*4) & (NT - 1);
          int bb = (m0 + wm*64) >> 11;
          int n = n0 + wn*64 + nt*16 + l15;
          int hh = n >> 6, hd = n & (NHD - 1);
          uint32_t pk = 0;
          #pragma unroll
          for (int r = 0; r < 4; ++r) {
            uint32_t q = (uint32_t)(uint8_t)sat8(A_PROJ * (float)acc[z][mt][nt][r] + bf[nt]);
            pk |= q << (8 * r);
          }
          size_t bh = (size_t)bb * NH + hh;
          *(uint32_t*)&Vt[(bh * NHD + hd) * NT + tbase] = pk;
        }
    } else {
      int8_t* O = (z == 0) ? Qh : Kh;
      #pragma unroll
      for (int mt = 0; mt < 4; ++mt)
        #pragma unroll
        for (int nt = 0; nt < 4; ++nt)
          #pragma unroll
          for (int r = 0; r < 4; ++r) {
            int m = m0 + wm*64 + mt*16 + quad*4 + r;     // C/D: row = quad*4+reg
            int n = n0 + wn*64 + nt*16 + l15;            //      col = lane&15
            int8_t q = sat8(A_PROJ * (float)acc[z][mt][nt][r] + bf[nt]);
            int bb = m >> 11, t = m & (NT - 1);
            int hh = n >> 6, hd = n & (NHD - 1);
            size_t bh = (size_t)bb * NH + hh;
            O[(bh * NT + t) * NHD + hd] = q;
          }
    }
  }
}

// ---------------- fused causal attention (v9: wave-paired 64-row tiles) ----------------
// R17: R16's counters showed attn occupancy 49.7% is the causal-triangle TAIL:
// total waves (8192) == chip capacity exactly; the heaviest block (64 steps)
// runs alone after its CU's light blocks (avg 34) drain -> half the kernel at
// 2 waves/SIMD. Fix: uniform blocks. Block = 256 threads (4 waves x 16 t-rows
// = one 64-row tile), processing tiles x=bx then x=31-bx sequentially: steps
// per pass = (bx+1)+(32-bx) = 33 for EVERY block -> zero tail, any dispatch
// mapping. v8 internals kept (prefetch-dbuf, 1 barrier/step, wave-local lsum,
// private Ps32). 64-row tiling simplifies masks: diag <=> st==x, no skips.
// LDS 21.5KB; grid (16,64)=1024 blocks = 4/CU, constant ~16 busy waves/CU.
__global__ __launch_bounds__(256, 4) void attn_fused(
    const int8_t* __restrict__ Qh, const int8_t* __restrict__ Kh, const int8_t* __restrict__ Vt,
    int8_t* __restrict__ AO)
{
  __shared__ __align__(16) int8_t Ksd[2][64][64];     // stored chunk = logical ^ ((row>>1)&3)
  __shared__ __align__(16) int8_t Vsd[2][64][64];     // same swizzle family
  __shared__ __align__(16) uint32_t Ps32[4][16][20];  // per-wave P (u32-packed, +pad)

  const int bx = blockIdx.x;           // 0..15
  const int bh = blockIdx.y;           // 0..63
  const int tid = threadIdx.x, lane = tid & 63, wave = tid >> 6;   // wave 0..3
  const int l15 = lane & 15, quad = lane >> 4;
  const v4i vzero = {0, 0, 0, 0};
  const float MAGIC = 12582912.0f;    // 1.5*2^23: low byte of fmaf(e,linv,MAGIC) = rne(e*linv)
  const float C2 = 2.8853900817779268e-05f;  // A_QK * log2(e): exp(A_QK x) = exp2(C2 x)

  const int8_t* Qp = Qh + (size_t)bh * NT * NHD;
  const int8_t* Kp = Kh + (size_t)bh * NT * NHD;
  const int8_t* Vp = Vt + (size_t)bh * NHD * NT;
  const int bb = bh >> 5, hhead = bh & (NH - 1);

  const int strow = lane >> 2;                                // staging row in 16-block
  const int stcol = (((lane & 3) ^ ((lane >> 3) & 3)) * 16);  // pre-swizzled source chunk
  const int fcol  = (quad ^ ((l15 >> 1) & 3)) * 16;           // frag-read stored chunk

  for (int half = 0; half < 2; ++half) {
    const int x = half ? (31 - bx) : bx;   // 64-row tile index, 0..31
    const int t0 = x * 64;
    const int tw = t0 + wave * 16;         // wave's min t
    const int tme = tw + l15;              // lane's t row (mask compare)

    v4i qf = *(const v4i*)&Qp[(size_t)(tw + l15) * NHD + quad * 16];

    // ---- pass 1: l = sum_s exp(score); bounded scores -> no max subtraction
    float ls0 = 0.f, ls1 = 0.f, ls2 = 0.f, ls3 = 0.f;
    gl2lds16(&Kp[(size_t)(wave*16 + strow) * NHD + stcol], &Ksd[0][wave*16][0]);
    __syncthreads();
    int cur = 0;
    for (int st = 0; st <= x; ++st) {
      if (st < x)
        gl2lds16(&Kp[(size_t)((st+1)*64 + wave*16 + strow) * NHD + stcol],
                 &Ksd[cur ^ 1][wave*16][0]);
      const int s0 = st * 64;
      v4i kf[4];
      #pragma unroll
      for (int mt = 0; mt < 4; ++mt) kf[mt] = *(const v4i*)&Ksd[cur][mt*16 + l15][fcol];
      if (st == x) {                         // diagonal tile: per-elem mask
        #pragma unroll
        for (int mt = 0; mt < 4; ++mt) {
          v4i sa = __builtin_amdgcn_mfma_i32_16x16x64_i8(kf[mt], qf, vzero, 0, 0, 0);
          const int sb = s0 + mt*16 + quad*4;
          ls0 += (sb + 0 <= tme) ? exp2_fast(C2 * (float)sa[0]) : 0.f;
          ls1 += (sb + 1 <= tme) ? exp2_fast(C2 * (float)sa[1]) : 0.f;
          ls2 += (sb + 2 <= tme) ? exp2_fast(C2 * (float)sa[2]) : 0.f;
          ls3 += (sb + 3 <= tme) ? exp2_fast(C2 * (float)sa[3]) : 0.f;
        }
      } else {                               // fully valid
        #pragma unroll
        for (int mt = 0; mt < 4; ++mt) {
          v4i sa = __builtin_amdgcn_mfma_i32_16x16x64_i8(kf[mt], qf, vzero, 0, 0, 0);
          ls0 += exp2_fast(C2 * (float)sa[0]);
          ls1 += exp2_fast(C2 * (float)sa[1]);
          ls2 += exp2_fast(C2 * (float)sa[2]);
          ls3 += exp2_fast(C2 * (float)sa[3]);
        }
      }
      __syncthreads();
      cur ^= 1;
    }
    float lsum = (ls0 + ls1) + (ls2 + ls3);
    lsum += __shfl_xor(lsum, 16, 64);   // reduce over quads (same l15 = same t)
    lsum += __shfl_xor(lsum, 32, 64);
    const float linv = 127.0f / lsum;

    // ---- pass 2: p_i8 = rne(127*e/l) via magic trick; PV int8 MFMA accumulate
    v4i accv[4];
    #pragma unroll
    for (int jj = 0; jj < 4; ++jj) accv[jj] = vzero;

    gl2lds16(&Kp[(size_t)(wave*16 + strow) * NHD + stcol], &Ksd[0][wave*16][0]);
    gl2lds16(&Vp[(size_t)(wave*16 + strow) * NT + stcol], &Vsd[0][wave*16][0]);
    __syncthreads();
    cur = 0;
    for (int st = 0; st <= x; ++st) {
      if (st < x) {
        gl2lds16(&Kp[(size_t)((st+1)*64 + wave*16 + strow) * NHD + stcol],
                 &Ksd[cur ^ 1][wave*16][0]);
        gl2lds16(&Vp[(size_t)(wave*16 + strow) * NT + (st+1)*64 + stcol],
                 &Vsd[cur ^ 1][wave*16][0]);
      }
      const int s0 = st * 64;
      v4i kf[4];
      #pragma unroll
      for (int mt = 0; mt < 4; ++mt) kf[mt] = *(const v4i*)&Ksd[cur][mt*16 + l15][fcol];
      if (st == x) {
        #pragma unroll
        for (int mt = 0; mt < 4; ++mt) {
          v4i sa = __builtin_amdgcn_mfma_i32_16x16x64_i8(kf[mt], qf, vzero, 0, 0, 0);
          const int sb = s0 + mt*16 + quad*4;
          float e0 = (sb + 0 <= tme) ? exp2_fast(C2 * (float)sa[0]) : 0.f;
          float e1 = (sb + 1 <= tme) ? exp2_fast(C2 * (float)sa[1]) : 0.f;
          float e2 = (sb + 2 <= tme) ? exp2_fast(C2 * (float)sa[2]) : 0.f;
          float e3 = (sb + 3 <= tme) ? exp2_fast(C2 * (float)sa[3]) : 0.f;
          Ps32[wave][l15][mt*4 + quad] =
              pack_lo4(fmaf(e0, linv, MAGIC), fmaf(e1, linv, MAGIC),
                       fmaf(e2, linv, MAGIC), fmaf(e3, linv, MAGIC));
        }
      } else {
        #pragma unroll
        for (int mt = 0; mt < 4; ++mt) {
          v4i sa = __builtin_amdgcn_mfma_i32_16x16x64_i8(kf[mt], qf, vzero, 0, 0, 0);
          float f0 = fmaf(exp2_fast(C2 * (float)sa[0]), linv, MAGIC);
          float f1 = fmaf(exp2_fast(C2 * (float)sa[1]), linv, MAGIC);
          float f2 = fmaf(exp2_fast(C2 * (float)sa[2]), linv, MAGIC);
          float f3 = fmaf(exp2_fast(C2 * (float)sa[3]), linv, MAGIC);
          Ps32[wave][l15][mt*4 + quad] = pack_lo4(f0, f1, f2, f3);
        }
      }
      // wave-private LDS RAW: same-wave DS ordering + compiler lgkmcnt — no barrier
      v4i ap = *(const v4i*)&Ps32[wave][l15][quad*4];
      #pragma unroll
      for (int nt2 = 0; nt2 < 4; ++nt2) {
        v4i bvv = *(const v4i*)&Vsd[cur][nt2*16 + l15][fcol];
        accv[nt2] = __builtin_amdgcn_mfma_i32_16x16x64_i8(ap, bvv, accv[nt2], 0, 0, 0);
      }
      __syncthreads();
      cur ^= 1;
    }

    // epilogue: AO[b][t][h*64+d];  C/D: row(quad*4+r)=t-local, col(l15)=d-local
    #pragma unroll
    for (int nt2 = 0; nt2 < 4; ++nt2)
      #pragma unroll
      for (int r = 0; r < 4; ++r) {
        int t = tw + quad*4 + r;
        int d = nt2*16 + l15;
        AO[((size_t)bb * NT + t) * ND + hhead * NHD + d] = sat8(A_PV * (float)accv[nt2][r]);
      }
  }
}

// ---------------- out projection: out = A_OUT * AO @ Wo^T + bo (fp32) ----------------
// R12 structure (2-buffer prefetch, 1 barrier/step) + XCD-region swizzle.
__global__ __launch_bounds__(256) void gemm_out(
    const int8_t* __restrict__ X, const int8_t* __restrict__ W,
    const float* __restrict__ bo, float* __restrict__ out)
{
  __shared__ __align__(16) int8_t As[2][128][64];
  __shared__ __align__(16) int8_t Bs[2][128][64];
  int bx, by;
  xcd_map(blockIdx.x + 32 * blockIdx.y, bx, by);
  const int m0 = bx * 128, n0 = by * 128;
  const int tid = threadIdx.x, lane = tid & 63, wave = tid >> 6;
  const int wm = wave >> 1, wn = wave & 1;
  const int l15 = lane & 15, quad = lane >> 4;
  const int srow = lane >> 2;
  const int scol = (((lane & 3) ^ ((lane >> 3) & 3)) * 16);
  const int rqcol = (quad ^ ((l15 >> 1) & 3)) * 16;

  const int8_t* srcp[4];
  int8_t* dstp[4];
  #pragma unroll
  for (int j = 0; j < 4; ++j) {
    int slot = j * 4 + wave;
    int rblk = slot & 7;
    int row = rblk * 16 + srow;
    if (slot < 8) { srcp[j] = &X[(size_t)(m0 + row) * ND + scol]; dstp[j] = &As[0][rblk*16][0]; }
    else          { srcp[j] = &W[(size_t)(n0 + row) * ND + scol]; dstp[j] = &Bs[0][rblk*16][0]; }
  }

  v4i acc[4][4];
  const v4i vzero = {0, 0, 0, 0};
  #pragma unroll
  for (int i = 0; i < 4; ++i)
    #pragma unroll
    for (int j = 0; j < 4; ++j) acc[i][j] = vzero;

  #pragma unroll
  for (int j = 0; j < 4; ++j) gl2lds16(srcp[j], dstp[j]);
  __syncthreads();

  int cur = 0;
  for (int k0 = 64; k0 <= ND; k0 += 64) {
    if (k0 < ND) {
      const int boff = (cur ^ 1) * 8192;
      #pragma unroll
      for (int j = 0; j < 4; ++j) gl2lds16(srcp[j] + k0, dstp[j] + boff);
    }
    v4i a[4], b[4];
    #pragma unroll
    for (int mt = 0; mt < 4; ++mt) a[mt] = *(const v4i*)&As[cur][wm*64 + mt*16 + l15][rqcol];
    #pragma unroll
    for (int nt = 0; nt < 4; ++nt) b[nt] = *(const v4i*)&Bs[cur][wn*64 + nt*16 + l15][rqcol];
    #pragma unroll
    for (int mt = 0; mt < 4; ++mt)
      #pragma unroll
      for (int nt = 0; nt < 4; ++nt)
        acc[mt][nt] = __builtin_amdgcn_mfma_i32_16x16x64_i8(a[mt], b[nt], acc[mt][nt], 0, 0, 0);
    __syncthreads();
    cur ^= 1;
  }

  float bf[4];
  #pragma unroll
  for (int nt = 0; nt < 4; ++nt) bf[nt] = bo[n0 + wn*64 + nt*16 + l15];

  #pragma unroll
  for (int mt = 0; mt < 4; ++mt)
    #pragma unroll
    for (int nt = 0; nt < 4; ++nt)
      #pragma unroll
      for (int r = 0; r < 4; ++r) {
        int m = m0 + wm*64 + mt*16 + quad*4 + r;
        int n = n0 + wn*64 + nt*16 + l15;
        out[(size_t)m * ND + n] = A_OUT * (float)acc[mt][nt][r] + bf[nt];
      }
}

extern "C" void kernel_launch(void* const* d_in, const int* in_sizes, int n_in,
                              void* d_out, int out_size, void* d_ws, size_t ws_size,
                              hipStream_t stream)
{
  const int*   hs  = (const int*)d_in[0];
  // d_in[1] = attention_mask: causal triu(-1e9) — applied structurally (s>t => p=0)
  const int*   Wq  = (const int*)d_in[2];
  const int*   bq  = (const int*)d_in[3];
  const int*   Wk  = (const int*)d_in[4];
  const int*   bkb = (const int*)d_in[5];
  const int*   Wv  = (const int*)d_in[6];
  const int*   bvb = (const int*)d_in[7];
  const int*   Wo  = (const int*)d_in[8];
  const float* bo  = (const float*)d_in[9];
  float* out = (float*)d_out;

  char* ws = (char*)d_ws;
  const size_t SZ_X = (size_t)NM * ND;              // 8 MiB
  const size_t SZ_W = (size_t)ND * ND;              // 4 MiB
  const size_t SZ_H = (size_t)NB * NH * NT * NHD;   // 8 MiB
  int8_t* Xp  = (int8_t*)ws;           // reused as AO after qkv gemm completes
  int8_t* Wqp = (int8_t*)(ws + SZ_X);
  int8_t* Wkp = Wqp + SZ_W;
  int8_t* Wvp = Wkp + SZ_W;
  int8_t* Wop = Wvp + SZ_W;
  int8_t* Qh  = Wop + SZ_W;
  int8_t* Kh  = Qh + SZ_H;
  int8_t* Vt  = Kh + SZ_H;
  int8_t* AO  = Xp;                    // alias: total ws use ~50.4 MB

  const int ntot = (int)(SZ_X/4 + 4 * (SZ_W/4));
  pack_all<<<(ntot + 255) / 256, 256, 0, stream>>>(hs, Wq, Wk, Wv, Wo,
                                                   Xp, Wqp, Wkp, Wvp, Wop);

  gemm_qkv<<<dim3(32, 16), 256, 0, stream>>>(Xp, Wqp, Wkp, Wvp, bq, bkb, bvb, Qh, Kh, Vt);
  attn_fused<<<dim3(16, NB*NH), 256, 0, stream>>>(Qh, Kh, Vt, AO);
  gemm_out<<<dim3(NM/128, ND/128), 256, 0, stream>>>(AO, Wop, bo, out);
}